// Round 7
// baseline (467.105 us; speedup 1.0000x reference)
//
#include <hip/hip_runtime.h>
#include <math.h>

// Problem constants (B=16, S=2048, L=E=512, N=2048)
#define BS_TOK 32768
#define DIM 512
#define NCODE 2048

typedef _Float16 f16x8 __attribute__((ext_vector_type(8)));
typedef _Float16 f16x4 __attribute__((ext_vector_type(4)));
typedef float f32x16 __attribute__((ext_vector_type(16)));

#define LDH 40  // halves per LDS row: 32 data + 8 pad = 80 B

// raw barrier + explicit LDS fence: does NOT drain vmcnt, so prefetch
// global loads stay in flight across the barrier.
#define LGKM0_FENCE asm volatile("s_waitcnt lgkmcnt(0)" ::: "memory")
#define SBAR __builtin_amdgcn_s_barrier()

// ---------------- row L2 normalize + fp16 hi/lo split (codebook) -----
__global__ __launch_bounds__(256) void k_rownorm_split(
    const float* __restrict__ in, _Float16* __restrict__ hi,
    _Float16* __restrict__ lo, int rstride) {
  const int r = blockIdx.x;
  const int t = threadIdx.x;
  const float* row = in + (size_t)r * DIM;
  float v0 = row[t];
  float v1 = row[t + 256];
  float s = v0 * v0 + v1 * v1;
#pragma unroll
  for (int off = 32; off > 0; off >>= 1) s += __shfl_down(s, off, 64);
  __shared__ float ls[4];
  if ((t & 63) == 0) ls[t >> 6] = s;
  __syncthreads();
  float tot = ls[0] + ls[1] + ls[2] + ls[3];
  float sc = 1.0f / fmaxf(sqrtf(tot), 1e-12f);
  float x0 = v0 * sc, x1 = v1 * sc;
  _Float16 h0 = (_Float16)x0;
  _Float16 h1 = (_Float16)x1;
  _Float16 e0 = (_Float16)((x0 - (float)h0) * 2048.0f);
  _Float16 e1 = (_Float16)((x1 - (float)h1) * 2048.0f);
  _Float16* hrow = hi + (size_t)r * rstride;
  _Float16* lrow = lo + (size_t)r * rstride;
  hrow[t] = h0;
  hrow[t + 256] = h1;
  lrow[t] = e0;
  lrow[t + 256] = e1;
}

// ---------------- fp32 -> fp16 hi/lo elementwise split (weights) ------
__global__ __launch_bounds__(256) void k_split_w(const float* __restrict__ w,
                                                 _Float16* __restrict__ hi,
                                                 _Float16* __restrict__ lo) {
  int t = (blockIdx.x * 256 + threadIdx.x) * 4;
  float4 v = *(const float4*)(w + t);
  f16x4 h, l;
  h.x = (_Float16)v.x; l.x = (_Float16)((v.x - (float)h.x) * 2048.0f);
  h.y = (_Float16)v.y; l.y = (_Float16)((v.y - (float)h.y) * 2048.0f);
  h.z = (_Float16)v.z; l.z = (_Float16)((v.z - (float)h.z) * 2048.0f);
  h.w = (_Float16)v.w; l.w = (_Float16)((v.w - (float)h.w) * 2048.0f);
  *(f16x4*)(hi + t) = h;
  *(f16x4*)(lo + t) = l;
}

// ---------------- MFMA split GEMM: input projection -------------------
// Epilogue FUSED: writes zf16 packed rows [hi 512 | lo 512] directly
// (no normalization — argmax over codes is scale-invariant in zf).
__global__ __launch_bounds__(256, 2) void k_gemm_mfma_in(
    const float* __restrict__ A, const _Float16* __restrict__ Bhi,
    const _Float16* __restrict__ Blo, const float* __restrict__ bias,
    _Float16* __restrict__ zf16) {
  __shared__ __align__(16) _Float16 sm[2][4][128 * LDH];  // 81920 B, 2 blk/CU
  const int tid = threadIdx.x;
  const int w = tid >> 6, l = tid & 63;
  const int wm = w >> 1, wn = w & 1;
  const int lm = l & 31, lh = l >> 5;
  const int m0 = blockIdx.y * 128;
  const int n0 = blockIdx.x * 128;
  const int arow = tid >> 3;
  const int ac4 = (tid & 7) << 2;
  const int brow = tid >> 2;
  const int bq = (tid & 3) << 3;

  f32x16 aHH[2][2], aX[2][2];
#pragma unroll
  for (int mb = 0; mb < 2; ++mb)
#pragma unroll
    for (int nb = 0; nb < 2; ++nb) {
      aHH[mb][nb] = (f32x16)0.0f;
      aX[mb][nb] = (f32x16)0.0f;
    }

  float4 ar[4];
  f16x8 brh[2], brl[2];

  auto LOADS = [&](int kt) {
#pragma unroll
    for (int i = 0; i < 4; ++i)
      ar[i] =
          *(const float4*)(A + (size_t)(m0 + arow + 32 * i) * DIM + kt * 32 + ac4);
#pragma unroll
    for (int i = 0; i < 2; ++i) {
      const size_t g = (size_t)(n0 + brow + 64 * i) * DIM + kt * 32 + bq;
      brh[i] = *(const f16x8*)(Bhi + g);
      brl[i] = *(const f16x8*)(Blo + g);
    }
  };
  auto WRITES = [&](int b) {
#pragma unroll
    for (int i = 0; i < 4; ++i) {
      f16x4 h, lo4;
      h.x = (_Float16)ar[i].x; lo4.x = (_Float16)((ar[i].x - (float)h.x) * 2048.0f);
      h.y = (_Float16)ar[i].y; lo4.y = (_Float16)((ar[i].y - (float)h.y) * 2048.0f);
      h.z = (_Float16)ar[i].z; lo4.z = (_Float16)((ar[i].z - (float)h.z) * 2048.0f);
      h.w = (_Float16)ar[i].w; lo4.w = (_Float16)((ar[i].w - (float)h.w) * 2048.0f);
      *(f16x4*)(&sm[b][0][(arow + 32 * i) * LDH + ac4]) = h;
      *(f16x4*)(&sm[b][1][(arow + 32 * i) * LDH + ac4]) = lo4;
    }
#pragma unroll
    for (int i = 0; i < 2; ++i) {
      *(f16x8*)(&sm[b][2][(brow + 64 * i) * LDH + bq]) = brh[i];
      *(f16x8*)(&sm[b][3][(brow + 64 * i) * LDH + bq]) = brl[i];
    }
  };

  LOADS(0);
  WRITES(0);
  LOADS(1);
  LGKM0_FENCE;
  SBAR;
  int cur = 0;
  const int NT = DIM / 32;  // 16
  for (int t = 0; t < NT; ++t) {
    if (t < NT - 1) WRITES(cur ^ 1);
    if (t < NT - 2) LOADS(t + 2);
#pragma unroll
    for (int c = 0; c < 2; ++c) {
      const int ko = c * 16 + lh * 8;
      f16x8 ah[2], al[2], bh[2], bl[2];
#pragma unroll
      for (int mb = 0; mb < 2; ++mb) {
        int r = wm * 64 + mb * 32 + lm;
        ah[mb] = *(const f16x8*)(&sm[cur][0][r * LDH + ko]);
        al[mb] = *(const f16x8*)(&sm[cur][1][r * LDH + ko]);
      }
#pragma unroll
      for (int nb = 0; nb < 2; ++nb) {
        int r = wn * 64 + nb * 32 + lm;
        bh[nb] = *(const f16x8*)(&sm[cur][2][r * LDH + ko]);
        bl[nb] = *(const f16x8*)(&sm[cur][3][r * LDH + ko]);
      }
#pragma unroll
      for (int mb = 0; mb < 2; ++mb)
#pragma unroll
        for (int nb = 0; nb < 2; ++nb) {
          aHH[mb][nb] = __builtin_amdgcn_mfma_f32_32x32x16_f16(
              ah[mb], bh[nb], aHH[mb][nb], 0, 0, 0);
          aX[mb][nb] = __builtin_amdgcn_mfma_f32_32x32x16_f16(
              ah[mb], bl[nb], aX[mb][nb], 0, 0, 0);
          aX[mb][nb] = __builtin_amdgcn_mfma_f32_32x32x16_f16(
              al[mb], bh[nb], aX[mb][nb], 0, 0, 0);
        }
    }
    LGKM0_FENCE;
    SBAR;
    cur ^= 1;
  }
#pragma unroll
  for (int nb = 0; nb < 2; ++nb) {
    int n = n0 + wn * 64 + nb * 32 + lm;
    float bv = bias[n];
#pragma unroll
    for (int mb = 0; mb < 2; ++mb)
#pragma unroll
      for (int r = 0; r < 16; ++r) {
        int m = m0 + wm * 64 + mb * 32 + (r & 3) + 8 * (r >> 2) + 4 * lh;
        float val = aHH[mb][nb][r] + aX[mb][nb][r] * (1.0f / 2048.0f) + bv;
        _Float16 h = (_Float16)val;
        _Float16 lo = (_Float16)((val - (float)h) * 2048.0f);
        zf16[(size_t)m * 1024 + n] = h;
        zf16[(size_t)m * 1024 + 512 + n] = lo;
      }
  }
}

// ---------------- MFMA split GEMM: codebook output table --------------
// table[c,:] = emb_n[c] @ W_out^T + b_out for ALL 2048 codes (1/16 the
// FLOPs of the per-token gather GEMM; gather commutes with linear map).
__global__ __launch_bounds__(256, 2) void k_gemm_codebook(
    const _Float16* __restrict__ Ahi, const _Float16* __restrict__ Alo,
    const _Float16* __restrict__ Bhi, const _Float16* __restrict__ Blo,
    const float* __restrict__ bias, float* __restrict__ table) {
  __shared__ __align__(16) _Float16 sm[2][4][128 * LDH];  // 81920 B
  const int tid = threadIdx.x;
  const int w = tid >> 6, l = tid & 63;
  const int wm = w >> 1, wn = w & 1;
  const int lm = l & 31, lh = l >> 5;
  const int m0 = blockIdx.y * 128;
  const int n0 = blockIdx.x * 128;
  const int brow = tid >> 2;
  const int bq = (tid & 3) << 3;

  f32x16 aHH[2][2], aX[2][2];
#pragma unroll
  for (int mb = 0; mb < 2; ++mb)
#pragma unroll
    for (int nb = 0; nb < 2; ++nb) {
      aHH[mb][nb] = (f32x16)0.0f;
      aX[mb][nb] = (f32x16)0.0f;
    }

  f16x8 arh[2], arl[2], brh[2], brl[2];

  auto LOADS = [&](int kt) {
    const int kc = kt * 32 + bq;
#pragma unroll
    for (int i = 0; i < 2; ++i) {
      const size_t ga = (size_t)(m0 + brow + 64 * i) * DIM + kc;
      arh[i] = *(const f16x8*)(Ahi + ga);
      arl[i] = *(const f16x8*)(Alo + ga);
      const size_t g = (size_t)(n0 + brow + 64 * i) * DIM + kc;
      brh[i] = *(const f16x8*)(Bhi + g);
      brl[i] = *(const f16x8*)(Blo + g);
    }
  };
  auto WRITES = [&](int b) {
#pragma unroll
    for (int i = 0; i < 2; ++i) {
      *(f16x8*)(&sm[b][0][(brow + 64 * i) * LDH + bq]) = arh[i];
      *(f16x8*)(&sm[b][1][(brow + 64 * i) * LDH + bq]) = arl[i];
      *(f16x8*)(&sm[b][2][(brow + 64 * i) * LDH + bq]) = brh[i];
      *(f16x8*)(&sm[b][3][(brow + 64 * i) * LDH + bq]) = brl[i];
    }
  };

  LOADS(0);
  WRITES(0);
  LOADS(1);
  LGKM0_FENCE;
  SBAR;
  int cur = 0;
  const int NT = DIM / 32;
  for (int t = 0; t < NT; ++t) {
    if (t < NT - 1) WRITES(cur ^ 1);
    if (t < NT - 2) LOADS(t + 2);
#pragma unroll
    for (int c = 0; c < 2; ++c) {
      const int ko = c * 16 + lh * 8;
      f16x8 ah[2], al[2], bh[2], bl[2];
#pragma unroll
      for (int mb = 0; mb < 2; ++mb) {
        int r = wm * 64 + mb * 32 + lm;
        ah[mb] = *(const f16x8*)(&sm[cur][0][r * LDH + ko]);
        al[mb] = *(const f16x8*)(&sm[cur][1][r * LDH + ko]);
      }
#pragma unroll
      for (int nb = 0; nb < 2; ++nb) {
        int r = wn * 64 + nb * 32 + lm;
        bh[nb] = *(const f16x8*)(&sm[cur][2][r * LDH + ko]);
        bl[nb] = *(const f16x8*)(&sm[cur][3][r * LDH + ko]);
      }
#pragma unroll
      for (int mb = 0; mb < 2; ++mb)
#pragma unroll
        for (int nb = 0; nb < 2; ++nb) {
          aHH[mb][nb] = __builtin_amdgcn_mfma_f32_32x32x16_f16(
              ah[mb], bh[nb], aHH[mb][nb], 0, 0, 0);
          aX[mb][nb] = __builtin_amdgcn_mfma_f32_32x32x16_f16(
              ah[mb], bl[nb], aX[mb][nb], 0, 0, 0);
          aX[mb][nb] = __builtin_amdgcn_mfma_f32_32x32x16_f16(
              al[mb], bh[nb], aX[mb][nb], 0, 0, 0);
        }
    }
    LGKM0_FENCE;
    SBAR;
    cur ^= 1;
  }
#pragma unroll
  for (int nb = 0; nb < 2; ++nb) {
    int n = n0 + wn * 64 + nb * 32 + lm;
    float bv = bias[n];
#pragma unroll
    for (int mb = 0; mb < 2; ++mb)
#pragma unroll
      for (int r = 0; r < 16; ++r) {
        int m = m0 + wm * 64 + mb * 32 + (r & 3) + 8 * (r >> 2) + 4 * lh;
        table[(size_t)m * DIM + n] =
            aHH[mb][nb][r] + aX[mb][nb][r] * (1.0f / 2048.0f) + bv;
      }
  }
}

// ---------------- gather + straight-through copy ----------------------
// zq[m,:] = z[m,:] + (table[idx[m],:] - z[m,:])   (strict fp32, as ref)
__global__ __launch_bounds__(256) void k_gather_st(
    const float* __restrict__ z, const float* __restrict__ table,
    const int* __restrict__ idx, float* __restrict__ out) {
  int g = blockIdx.x * 256 + threadIdx.x;  // one float4 per thread
  int m = g >> 7;
  int c = (g & 127) << 2;
  int n = idx[m];
  float4 t = *(const float4*)(table + (size_t)n * DIM + c);
  float4 zv = *(const float4*)(z + (size_t)m * DIM + c);
  float4 o;
  o.x = zv.x + (t.x - zv.x);
  o.y = zv.y + (t.y - zv.y);
  o.z = zv.z + (t.z - zv.z);
  o.w = zv.w + (t.w - zv.w);
  *(float4*)(out + (size_t)m * DIM + c) = o;
}

// ---------------- hi-only MFMA similarity + top-4 candidates ----------
// A-fragments loaded DIRECTLY global->VGPR with 1-K-step register
// prefetch (A is identical across all nt tiles — staging it through LDS
// was 8x-redundant and made the kernel LDS-throughput-bound). Only B
// (codes) goes through LDS, double-buffered, one raw barrier per K-step.
// LDS 33280 B (B bufs 2x10240 B; epilogue sC alias needs 33280).
#define SIMK_BM 128
#define SIMK_BN 128
#define NQUART 4
#define QCODES (NCODE / NQUART)  // 512

__global__ __launch_bounds__(256, 3) void k_sim_argmax(
    const _Float16* __restrict__ Apack,  // token rows: 1024 halves = hi|lo
    const _Float16* __restrict__ Bhi, unsigned* __restrict__ cand) {
  __shared__ __align__(16) _Float16 smem[16640];  // 33280 B
  float* sC = (float*)smem;  // epilogue alias: [128][65] fp32 = 33280 B

  const int tid = threadIdx.x;
  const int w = tid >> 6, l = tid & 63;
  const int wm = w >> 1, wn = w & 1;
  const int lm = l & 31, lh = l >> 5;
  const int q = blockIdx.x & (NQUART - 1);
  const int tokbase = (blockIdx.x >> 2) * SIMK_BM;
  const int code0 = q * QCODES;
  const int brow = tid >> 2;
  const int bq = (tid & 3) << 3;
  const int t_red = tid >> 1, h_red = tid & 1;

  unsigned e0 = 0, e1 = 0, e2 = 0, e3 = 0;  // top-4 keys, descending

  // per-lane direct A bases: row = tokbase + wm*64 + mb*32 + lm,
  // k-half-offset = t*32 + c*16 + lh*8 (t=16 prefetch lands in the row's
  // lo half — in-bounds, unused).
  const _Float16* aB0 =
      Apack + (size_t)(tokbase + wm * 64 + lm) * 1024 + lh * 8;
  const _Float16* aB1 = aB0 + 32 * 1024;

  f16x8 brh[2];
  auto LOADB = [&](int nt, int kt) {
    const int kc = kt * 32 + bq;
#pragma unroll
    for (int i = 0; i < 2; ++i)
      brh[i] =
          *(const f16x8*)(Bhi + (size_t)(code0 + nt + brow + 64 * i) * DIM + kc);
  };
  auto WRITEB = [&](int b) {
#pragma unroll
    for (int i = 0; i < 2; ++i)
      *(f16x8*)(&smem[b * 5120 + (brow + 64 * i) * LDH + bq]) = brh[i];
  };
  f16x8 aC[2][2], aN[2][2];  // [c][mb]
  auto LOADA = [&](int t, f16x8 (&a)[2][2]) {
#pragma unroll
    for (int c = 0; c < 2; ++c) {
      a[c][0] = *(const f16x8*)(aB0 + t * 32 + c * 16);
      a[c][1] = *(const f16x8*)(aB1 + t * 32 + c * 16);
    }
  };

  for (int nt = 0; nt < QCODES; nt += SIMK_BN) {
    f32x16 acc[2][2];
#pragma unroll
    for (int mb = 0; mb < 2; ++mb)
#pragma unroll
      for (int nb = 0; nb < 2; ++nb) acc[mb][nb] = (f32x16)0.0f;
    __syncthreads();  // prev epilogue's sC reads done before restaging
    LOADB(nt, 0);
    WRITEB(0);
    LOADB(nt, 1);
    LOADA(0, aC);
    LGKM0_FENCE;
    SBAR;

    // one K-step; cur is compile-time (even t -> buf0, odd t -> buf1)
    auto STEP = [&](int t, int cur, f16x8 (&aU)[2][2], f16x8 (&aP)[2][2]) {
      LOADA(t + 1, aP);              // global prefetch, in flight over MFMAs
      if (t < 15) WRITEB(cur ^ 1);   // B data for K-step t+1
      if (t < 14) LOADB(nt, t + 2);  // B prefetch, survives the barrier
#pragma unroll
      for (int c = 0; c < 2; ++c) {
        const int ko = c * 16 + lh * 8;
        f16x8 bh[2];
#pragma unroll
        for (int nb = 0; nb < 2; ++nb)
          bh[nb] = *(const f16x8*)(&smem[cur * 5120 +
                                         (wn * 64 + nb * 32 + lm) * LDH + ko]);
#pragma unroll
        for (int mb = 0; mb < 2; ++mb)
#pragma unroll
          for (int nb = 0; nb < 2; ++nb)
            acc[mb][nb] = __builtin_amdgcn_mfma_f32_32x32x16_f16(
                aU[c][mb], bh[nb], acc[mb][nb], 0, 0, 0);
      }
      LGKM0_FENCE;
      SBAR;
    };
    for (int t2 = 0; t2 < 16; t2 += 2) {
      STEP(t2, 0, aC, aN);
      STEP(t2 + 1, 1, aN, aC);
    }

    // epilogue: two n-halves through LDS; top-4 insertion scan
#pragma unroll
    for (int p = 0; p < 2; ++p) {
      __syncthreads();
      if (wn == p) {
#pragma unroll
        for (int mb = 0; mb < 2; ++mb)
#pragma unroll
          for (int nb = 0; nb < 2; ++nb) {
            int nl = nb * 32 + lm;
#pragma unroll
            for (int r = 0; r < 16; ++r) {
              int m = wm * 64 + mb * 32 + (r & 3) + 8 * (r >> 2) + 4 * lh;
              sC[m * 65 + nl] = acc[mb][nb][r];
            }
          }
      }
      __syncthreads();
      const float* rowp = &sC[t_red * 65 + h_red * 32];
      const int ncomp = 2047 - (code0 + nt + p * 64 + h_red * 32);
#pragma unroll
      for (int i = 0; i < 32; ++i) {
        float v = rowp[i];
        unsigned s = __float_as_uint(v);
        s = (s & 0x80000000u) ? ~s : (s | 0x80000000u);
        unsigned key = (s & 0xFFFFF800u) | (unsigned)(ncomp - i);
        if (key > e3) {  // rare after warm-up
          unsigned y = key, t2;
          t2 = e0 > y ? e0 : y; y = e0 > y ? y : e0; e0 = t2;
          t2 = e1 > y ? e1 : y; y = e1 > y ? y : e1; e1 = t2;
          t2 = e2 > y ? e2 : y; y = e2 > y ? y : e2; e2 = t2;
          e3 = e3 > y ? e3 : y;
        }
      }
    }
  }
  // merge the two half-lane lists (partition of this quarter's codes)
  unsigned o0 = __shfl_xor(e0, 1), o1 = __shfl_xor(e1, 1),
           o2 = __shfl_xor(e2, 1), o3 = __shfl_xor(e3, 1);
#define INS4(x)                                    \
  {                                                \
    unsigned y = (x), t2;                          \
    t2 = e0 > y ? e0 : y; y = e0 > y ? y : e0; e0 = t2; \
    t2 = e1 > y ? e1 : y; y = e1 > y ? y : e1; e1 = t2; \
    t2 = e2 > y ? e2 : y; y = e2 > y ? y : e2; e2 = t2; \
    e3 = e3 > y ? e3 : y;                          \
  }
  INS4(o0) INS4(o1) INS4(o2) INS4(o3)
  if (h_red == 0) {
    unsigned* cp = cand + ((size_t)(tokbase + t_red) * NQUART + q) * 4;
    cp[0] = e0; cp[1] = e1; cp[2] = e2; cp[3] = e3;
  }
}

// ---------------- exact refine over 16 candidates per token -----------
// Margin test scaled by ||zf_hi|| (zf is unnormalized):
//   split error per sim <= 2^-10 * ||zf||;  key truncation <= 2^-11*|v|.
//   THETA = 2.0e-3*||zf_hi|| + 2^-10*(|v1|+|v2|) + slop.
__global__ __launch_bounds__(256) void k_refine(
    const unsigned* __restrict__ cand, const _Float16* __restrict__ zf16,
    const _Float16* __restrict__ embhi, const _Float16* __restrict__ emblo,
    int* __restrict__ idx, float* __restrict__ idxf) {
  const int tok = (blockIdx.x << 2) + (threadIdx.x >> 6);
  const int lane = threadIdx.x & 63;
  // ||zf_hi||^2 across the wave (also warms cache for exact path)
  f16x8 zh8 = *(const f16x8*)(zf16 + (size_t)tok * 1024 + lane * 8);
  float ss = 0.0f;
#pragma unroll
  for (int j = 0; j < 8; ++j) {
    float x = (float)zh8[j];
    ss += x * x;
  }
#pragma unroll
  for (int off = 1; off < 64; off <<= 1) ss += __shfl_xor(ss, off);

  unsigned k32 = (lane < 16) ? cand[(size_t)tok * 16 + lane] : 0u;
  // wave-wide top-2 of the 16 keys
  unsigned m1 = k32, m2 = 0;
#pragma unroll
  for (int off = 1; off < 64; off <<= 1) {
    unsigned q1 = __shfl_xor(m1, off), q2 = __shfl_xor(m2, off);
    unsigned hi = m1 > q1 ? m1 : q1;
    unsigned lo = m1 > q1 ? q1 : m1;
    unsigned s2 = m2 > q2 ? m2 : q2;
    m2 = lo > s2 ? lo : s2;
    m1 = hi;
  }
  unsigned s1 = m1 & 0xFFFFF800u, s2e = m2 & 0xFFFFF800u;
  float v1 = __uint_as_float((s1 & 0x80000000u) ? (s1 & 0x7FFFFFFFu) : ~s1);
  float v2 = __uint_as_float((s2e & 0x80000000u) ? (s2e & 0x7FFFFFFFu) : ~s2e);
  float theta = 2.0e-3f * sqrtf(ss) +
                9.765625e-4f * (fabsf(v1) + fabsf(v2)) + 1e-6f;
  if (v1 - v2 >= theta) {
    if (lane == 0) {
      int n1 = 2047 - (int)(m1 & 0x7FFu);
      idx[tok] = n1;
      idxf[tok] = (float)n1;
    }
    return;
  }
  // exact path: lane -> (candidate c = lane&15, dim segment seg = lane>>4)
  const int c = lane & 15, seg = lane >> 4;
  unsigned ck = __shfl(k32, c);
  int n = 2047 - (int)(ck & 0x7FFu);
  const _Float16* zh = zf16 + (size_t)tok * 1024 + seg * 128;
  const _Float16* eh = embhi + (size_t)n * DIM + seg * 128;
  const _Float16* el = emblo + (size_t)n * DIM + seg * 128;
  float s = 0.0f;
#pragma unroll
  for (int d = 0; d < 128; d += 8) {
    f16x8 a = *(const f16x8*)(zh + d);
    f16x8 b = *(const f16x8*)(zh + 512 + d);
    f16x8 e = *(const f16x8*)(eh + d);
    f16x8 f = *(const f16x8*)(el + d);
#pragma unroll
    for (int j = 0; j < 8; ++j)
      s += ((float)a[j] + (float)b[j] * (1.0f / 2048.0f)) *
           ((float)e[j] + (float)f[j] * (1.0f / 2048.0f));
  }
  s += __shfl_xor(s, 16);
  s += __shfl_xor(s, 32);
  unsigned sb = __float_as_uint(s);
  sb = (sb & 0x80000000u) ? ~sb : (sb | 0x80000000u);
  unsigned long long kk =
      ((unsigned long long)sb << 32) | (unsigned)(2047 - n);
  if (lane >= 16) kk = 0ull;
#pragma unroll
  for (int off = 1; off < 16; off <<= 1) {
    unsigned long long o = __shfl_xor(kk, off);
    kk = o > kk ? o : kk;
  }
  if (lane == 0) {
    int nb = 2047 - (int)((unsigned)kk & 0x7FFu);
    idx[tok] = nb;
    idxf[tok] = (float)nb;
  }
}

extern "C" void kernel_launch(void* const* d_in, const int* in_sizes, int n_in,
                              void* d_out, int out_size, void* d_ws,
                              size_t ws_size, hipStream_t stream) {
  const float* z = (const float*)d_in[0];
  // d_in[1] = mask, unused
  const float* W_in = (const float*)d_in[2];
  const float* b_in = (const float*)d_in[3];
  const float* W_out = (const float*)d_in[4];
  const float* b_out = (const float*)d_in[5];
  const float* emb = (const float*)d_in[6];

  float* out = (float*)d_out;
  float* zq = out;                           // 32768*512 fp32 (final output)
  float* idxf = out + (size_t)BS_TOK * DIM;  // 32768 fp32 indices

  // ws layout (10.125 MB): embhi|emblo|winhi|winlo|wouthi|woutlo|idx|scratch
  // scratch holds cand (2 MB, dead after refine) then table (4 MB) overlaid.
  _Float16* embhi = (_Float16*)d_ws;
  _Float16* emblo = embhi + (size_t)NCODE * DIM;
  _Float16* winhi = emblo + (size_t)NCODE * DIM;
  _Float16* winlo = winhi + (size_t)DIM * DIM;
  _Float16* wouthi = winlo + (size_t)DIM * DIM;
  _Float16* woutlo = wouthi + (size_t)DIM * DIM;
  int* idx = (int*)(woutlo + (size_t)DIM * DIM);
  unsigned* cand = (unsigned*)(idx + BS_TOK);
  float* table = (float*)cand;  // overlay; written only after refine

  // zf16 packed rows [hi 512 | lo 512] live in the zq output region
  _Float16* zf16 = (_Float16*)zq;

  // 0) split weights
  k_split_w<<<DIM * DIM / 1024, 256, 0, stream>>>(W_in, winhi, winlo);
  k_split_w<<<DIM * DIM / 1024, 256, 0, stream>>>(W_out, wouthi, woutlo);
  // 1) normalize + split codebook rows -> ws
  k_rownorm_split<<<NCODE, 256, 0, stream>>>(emb, embhi, emblo, DIM);
  // 2) zf16 = split(z @ W_in^T + b_in)  (UNNORMALIZED; fused epilogue)
  k_gemm_mfma_in<<<dim3(DIM / 128, BS_TOK / 128), 256, 0, stream>>>(
      z, winhi, winlo, b_in, zf16);
  // 3) hi-only MFMA similarity -> top-4 candidates per (token, quarter)
  k_sim_argmax<<<(BS_TOK / SIMK_BM) * NQUART, 256, 0, stream>>>(zf16, embhi,
                                                                cand);
  // 4) exact refine -> idx (ws) + idxf (d_out)
  k_refine<<<BS_TOK / 4, 256, 0, stream>>>(cand, zf16, embhi, emblo, idx,
                                           idxf);
  // 5) codebook output table (2048 rows; overlays dead cand region)
  k_gemm_codebook<<<dim3(DIM / 128, NCODE / 128), 256, 0, stream>>>(
      embhi, emblo, wouthi, woutlo, b_out, table);
  // 6) zq = z + (table[idx] - z)  (overwrites zf16 region)
  k_gather_st<<<BS_TOK * (DIM / 4) / 256, 256, 0, stream>>>(z, table, idx,
                                                            zq);
}

// Round 8
// 402.837 us; speedup vs baseline: 1.1595x; 1.1595x over previous
//
#include <hip/hip_runtime.h>
#include <math.h>

// Problem constants (B=16, S=2048, L=E=512, N=2048)
#define BS_TOK 32768
#define DIM 512
#define NCODE 2048

typedef _Float16 f16x8 __attribute__((ext_vector_type(8)));
typedef _Float16 f16x4 __attribute__((ext_vector_type(4)));
typedef float f32x16 __attribute__((ext_vector_type(16)));

#define LDH 40  // halves per LDS row: 32 data + 8 pad = 80 B

// raw barrier + explicit LDS fence: does NOT drain vmcnt, so prefetch
// global loads stay in flight across the barrier.
#define LGKM0_FENCE asm volatile("s_waitcnt lgkmcnt(0)" ::: "memory")
#define SBAR __builtin_amdgcn_s_barrier()

// ---------------- row L2 normalize + fp16 hi/lo split (codebook) -----
__global__ __launch_bounds__(256) void k_rownorm_split(
    const float* __restrict__ in, _Float16* __restrict__ hi,
    _Float16* __restrict__ lo, int rstride) {
  const int r = blockIdx.x;
  const int t = threadIdx.x;
  const float* row = in + (size_t)r * DIM;
  float v0 = row[t];
  float v1 = row[t + 256];
  float s = v0 * v0 + v1 * v1;
#pragma unroll
  for (int off = 32; off > 0; off >>= 1) s += __shfl_down(s, off, 64);
  __shared__ float ls[4];
  if ((t & 63) == 0) ls[t >> 6] = s;
  __syncthreads();
  float tot = ls[0] + ls[1] + ls[2] + ls[3];
  float sc = 1.0f / fmaxf(sqrtf(tot), 1e-12f);
  float x0 = v0 * sc, x1 = v1 * sc;
  _Float16 h0 = (_Float16)x0;
  _Float16 h1 = (_Float16)x1;
  _Float16 e0 = (_Float16)((x0 - (float)h0) * 2048.0f);
  _Float16 e1 = (_Float16)((x1 - (float)h1) * 2048.0f);
  _Float16* hrow = hi + (size_t)r * rstride;
  _Float16* lrow = lo + (size_t)r * rstride;
  hrow[t] = h0;
  hrow[t + 256] = h1;
  lrow[t] = e0;
  lrow[t + 256] = e1;
}

// ---------------- fp32 -> fp16 hi/lo elementwise split (weights) ------
__global__ __launch_bounds__(256) void k_split_w(const float* __restrict__ w,
                                                 _Float16* __restrict__ hi,
                                                 _Float16* __restrict__ lo) {
  int t = (blockIdx.x * 256 + threadIdx.x) * 4;
  float4 v = *(const float4*)(w + t);
  f16x4 h, l;
  h.x = (_Float16)v.x; l.x = (_Float16)((v.x - (float)h.x) * 2048.0f);
  h.y = (_Float16)v.y; l.y = (_Float16)((v.y - (float)h.y) * 2048.0f);
  h.z = (_Float16)v.z; l.z = (_Float16)((v.z - (float)h.z) * 2048.0f);
  h.w = (_Float16)v.w; l.w = (_Float16)((v.w - (float)h.w) * 2048.0f);
  *(f16x4*)(hi + t) = h;
  *(f16x4*)(lo + t) = l;
}

// ---------------- MFMA split GEMM: input projection -------------------
// Epilogue FUSED: writes zf16 packed rows [hi 512 | lo 512] directly
// (no normalization — argmax over codes is scale-invariant in zf).
__global__ __launch_bounds__(256, 2) void k_gemm_mfma_in(
    const float* __restrict__ A, const _Float16* __restrict__ Bhi,
    const _Float16* __restrict__ Blo, const float* __restrict__ bias,
    _Float16* __restrict__ zf16) {
  __shared__ __align__(16) _Float16 sm[2][4][128 * LDH];  // 81920 B, 2 blk/CU
  const int tid = threadIdx.x;
  const int w = tid >> 6, l = tid & 63;
  const int wm = w >> 1, wn = w & 1;
  const int lm = l & 31, lh = l >> 5;
  const int m0 = blockIdx.y * 128;
  const int n0 = blockIdx.x * 128;
  const int arow = tid >> 3;
  const int ac4 = (tid & 7) << 2;
  const int brow = tid >> 2;
  const int bq = (tid & 3) << 3;

  f32x16 aHH[2][2], aX[2][2];
#pragma unroll
  for (int mb = 0; mb < 2; ++mb)
#pragma unroll
    for (int nb = 0; nb < 2; ++nb) {
      aHH[mb][nb] = (f32x16)0.0f;
      aX[mb][nb] = (f32x16)0.0f;
    }

  float4 ar[4];
  f16x8 brh[2], brl[2];

  auto LOADS = [&](int kt) {
#pragma unroll
    for (int i = 0; i < 4; ++i)
      ar[i] =
          *(const float4*)(A + (size_t)(m0 + arow + 32 * i) * DIM + kt * 32 + ac4);
#pragma unroll
    for (int i = 0; i < 2; ++i) {
      const size_t g = (size_t)(n0 + brow + 64 * i) * DIM + kt * 32 + bq;
      brh[i] = *(const f16x8*)(Bhi + g);
      brl[i] = *(const f16x8*)(Blo + g);
    }
  };
  auto WRITES = [&](int b) {
#pragma unroll
    for (int i = 0; i < 4; ++i) {
      f16x4 h, lo4;
      h.x = (_Float16)ar[i].x; lo4.x = (_Float16)((ar[i].x - (float)h.x) * 2048.0f);
      h.y = (_Float16)ar[i].y; lo4.y = (_Float16)((ar[i].y - (float)h.y) * 2048.0f);
      h.z = (_Float16)ar[i].z; lo4.z = (_Float16)((ar[i].z - (float)h.z) * 2048.0f);
      h.w = (_Float16)ar[i].w; lo4.w = (_Float16)((ar[i].w - (float)h.w) * 2048.0f);
      *(f16x4*)(&sm[b][0][(arow + 32 * i) * LDH + ac4]) = h;
      *(f16x4*)(&sm[b][1][(arow + 32 * i) * LDH + ac4]) = lo4;
    }
#pragma unroll
    for (int i = 0; i < 2; ++i) {
      *(f16x8*)(&sm[b][2][(brow + 64 * i) * LDH + bq]) = brh[i];
      *(f16x8*)(&sm[b][3][(brow + 64 * i) * LDH + bq]) = brl[i];
    }
  };

  LOADS(0);
  WRITES(0);
  LOADS(1);
  LGKM0_FENCE;
  SBAR;
  int cur = 0;
  const int NT = DIM / 32;  // 16
  for (int t = 0; t < NT; ++t) {
    if (t < NT - 1) WRITES(cur ^ 1);
    if (t < NT - 2) LOADS(t + 2);
#pragma unroll
    for (int c = 0; c < 2; ++c) {
      const int ko = c * 16 + lh * 8;
      f16x8 ah[2], al[2], bh[2], bl[2];
#pragma unroll
      for (int mb = 0; mb < 2; ++mb) {
        int r = wm * 64 + mb * 32 + lm;
        ah[mb] = *(const f16x8*)(&sm[cur][0][r * LDH + ko]);
        al[mb] = *(const f16x8*)(&sm[cur][1][r * LDH + ko]);
      }
#pragma unroll
      for (int nb = 0; nb < 2; ++nb) {
        int r = wn * 64 + nb * 32 + lm;
        bh[nb] = *(const f16x8*)(&sm[cur][2][r * LDH + ko]);
        bl[nb] = *(const f16x8*)(&sm[cur][3][r * LDH + ko]);
      }
#pragma unroll
      for (int mb = 0; mb < 2; ++mb)
#pragma unroll
        for (int nb = 0; nb < 2; ++nb) {
          aHH[mb][nb] = __builtin_amdgcn_mfma_f32_32x32x16_f16(
              ah[mb], bh[nb], aHH[mb][nb], 0, 0, 0);
          aX[mb][nb] = __builtin_amdgcn_mfma_f32_32x32x16_f16(
              ah[mb], bl[nb], aX[mb][nb], 0, 0, 0);
          aX[mb][nb] = __builtin_amdgcn_mfma_f32_32x32x16_f16(
              al[mb], bh[nb], aX[mb][nb], 0, 0, 0);
        }
    }
    LGKM0_FENCE;
    SBAR;
    cur ^= 1;
  }
#pragma unroll
  for (int nb = 0; nb < 2; ++nb) {
    int n = n0 + wn * 64 + nb * 32 + lm;
    float bv = bias[n];
#pragma unroll
    for (int mb = 0; mb < 2; ++mb)
#pragma unroll
      for (int r = 0; r < 16; ++r) {
        int m = m0 + wm * 64 + mb * 32 + (r & 3) + 8 * (r >> 2) + 4 * lh;
        float val = aHH[mb][nb][r] + aX[mb][nb][r] * (1.0f / 2048.0f) + bv;
        _Float16 h = (_Float16)val;
        _Float16 lo = (_Float16)((val - (float)h) * 2048.0f);
        zf16[(size_t)m * 1024 + n] = h;
        zf16[(size_t)m * 1024 + 512 + n] = lo;
      }
  }
}

// ---------------- MFMA split GEMM: codebook output table --------------
// table[c,:] = emb_n[c] @ W_out^T + b_out for ALL 2048 codes (1/16 the
// FLOPs of the per-token gather GEMM; gather commutes with linear map).
__global__ __launch_bounds__(256, 2) void k_gemm_codebook(
    const _Float16* __restrict__ Ahi, const _Float16* __restrict__ Alo,
    const _Float16* __restrict__ Bhi, const _Float16* __restrict__ Blo,
    const float* __restrict__ bias, float* __restrict__ table) {
  __shared__ __align__(16) _Float16 sm[2][4][128 * LDH];  // 81920 B
  const int tid = threadIdx.x;
  const int w = tid >> 6, l = tid & 63;
  const int wm = w >> 1, wn = w & 1;
  const int lm = l & 31, lh = l >> 5;
  const int m0 = blockIdx.y * 128;
  const int n0 = blockIdx.x * 128;
  const int brow = tid >> 2;
  const int bq = (tid & 3) << 3;

  f32x16 aHH[2][2], aX[2][2];
#pragma unroll
  for (int mb = 0; mb < 2; ++mb)
#pragma unroll
    for (int nb = 0; nb < 2; ++nb) {
      aHH[mb][nb] = (f32x16)0.0f;
      aX[mb][nb] = (f32x16)0.0f;
    }

  f16x8 arh[2], arl[2], brh[2], brl[2];

  auto LOADS = [&](int kt) {
    const int kc = kt * 32 + bq;
#pragma unroll
    for (int i = 0; i < 2; ++i) {
      const size_t ga = (size_t)(m0 + brow + 64 * i) * DIM + kc;
      arh[i] = *(const f16x8*)(Ahi + ga);
      arl[i] = *(const f16x8*)(Alo + ga);
      const size_t g = (size_t)(n0 + brow + 64 * i) * DIM + kc;
      brh[i] = *(const f16x8*)(Bhi + g);
      brl[i] = *(const f16x8*)(Blo + g);
    }
  };
  auto WRITES = [&](int b) {
#pragma unroll
    for (int i = 0; i < 2; ++i) {
      *(f16x8*)(&sm[b][0][(brow + 64 * i) * LDH + bq]) = arh[i];
      *(f16x8*)(&sm[b][1][(brow + 64 * i) * LDH + bq]) = arl[i];
      *(f16x8*)(&sm[b][2][(brow + 64 * i) * LDH + bq]) = brh[i];
      *(f16x8*)(&sm[b][3][(brow + 64 * i) * LDH + bq]) = brl[i];
    }
  };

  LOADS(0);
  WRITES(0);
  LOADS(1);
  LGKM0_FENCE;
  SBAR;
  int cur = 0;
  const int NT = DIM / 32;
  for (int t = 0; t < NT; ++t) {
    if (t < NT - 1) WRITES(cur ^ 1);
    if (t < NT - 2) LOADS(t + 2);
#pragma unroll
    for (int c = 0; c < 2; ++c) {
      const int ko = c * 16 + lh * 8;
      f16x8 ah[2], al[2], bh[2], bl[2];
#pragma unroll
      for (int mb = 0; mb < 2; ++mb) {
        int r = wm * 64 + mb * 32 + lm;
        ah[mb] = *(const f16x8*)(&sm[cur][0][r * LDH + ko]);
        al[mb] = *(const f16x8*)(&sm[cur][1][r * LDH + ko]);
      }
#pragma unroll
      for (int nb = 0; nb < 2; ++nb) {
        int r = wn * 64 + nb * 32 + lm;
        bh[nb] = *(const f16x8*)(&sm[cur][2][r * LDH + ko]);
        bl[nb] = *(const f16x8*)(&sm[cur][3][r * LDH + ko]);
      }
#pragma unroll
      for (int mb = 0; mb < 2; ++mb)
#pragma unroll
        for (int nb = 0; nb < 2; ++nb) {
          aHH[mb][nb] = __builtin_amdgcn_mfma_f32_32x32x16_f16(
              ah[mb], bh[nb], aHH[mb][nb], 0, 0, 0);
          aX[mb][nb] = __builtin_amdgcn_mfma_f32_32x32x16_f16(
              ah[mb], bl[nb], aX[mb][nb], 0, 0, 0);
          aX[mb][nb] = __builtin_amdgcn_mfma_f32_32x32x16_f16(
              al[mb], bh[nb], aX[mb][nb], 0, 0, 0);
        }
    }
    LGKM0_FENCE;
    SBAR;
    cur ^= 1;
  }
#pragma unroll
  for (int nb = 0; nb < 2; ++nb) {
    int n = n0 + wn * 64 + nb * 32 + lm;
    float bv = bias[n];
#pragma unroll
    for (int mb = 0; mb < 2; ++mb)
#pragma unroll
      for (int r = 0; r < 16; ++r) {
        int m = m0 + wm * 64 + mb * 32 + (r & 3) + 8 * (r >> 2) + 4 * lh;
        table[(size_t)m * DIM + n] =
            aHH[mb][nb][r] + aX[mb][nb][r] * (1.0f / 2048.0f) + bv;
      }
  }
}

// ---------------- gather + straight-through copy ----------------------
// zq[m,:] = z[m,:] + (table[idx[m],:] - z[m,:])   (strict fp32, as ref)
__global__ __launch_bounds__(256) void k_gather_st(
    const float* __restrict__ z, const float* __restrict__ table,
    const int* __restrict__ idx, float* __restrict__ out) {
  int g = blockIdx.x * 256 + threadIdx.x;  // one float4 per thread
  int m = g >> 7;
  int c = (g & 127) << 2;
  int n = idx[m];
  float4 t = *(const float4*)(table + (size_t)n * DIM + c);
  float4 zv = *(const float4*)(z + (size_t)m * DIM + c);
  float4 o;
  o.x = zv.x + (t.x - zv.x);
  o.y = zv.y + (t.y - zv.y);
  o.z = zv.z + (t.z - zv.z);
  o.w = zv.w + (t.w - zv.w);
  *(float4*)(out + (size_t)m * DIM + c) = o;
}

// ---------------- hi-only MFMA similarity + top-4 candidates ----------
// A AND B staged through LDS (A-direct regressed twice: r2, r7 — the
// consuming MFMA sits too close behind the L2 load at this occupancy).
// Scan fast-path: cached float bucket-floor t3f of the 4th-best key; per
// value only `v >= t3f` (floor property => no false negatives); encode +
// insert only on pass. 4 blocks/CU, LDS 40960 B.
#define SIMK_BM 128
#define SIMK_BN 128
#define NQUART 4
#define QCODES (NCODE / NQUART)  // 512

__global__ __launch_bounds__(256, 4) void k_sim_argmax(
    const _Float16* __restrict__ Apack,  // token rows: 1024 halves = hi|lo
    const _Float16* __restrict__ Bhi, unsigned* __restrict__ cand) {
  __shared__ __align__(16) _Float16 sm[2][2][128 * LDH];  // 40960 B
  float* sC = (float*)sm;  // epilogue alias: [128][65] fp32 = 33280 B

  const int tid = threadIdx.x;
  const int w = tid >> 6, l = tid & 63;
  const int wm = w >> 1, wn = w & 1;
  const int lm = l & 31, lh = l >> 5;
  const int q = blockIdx.x & (NQUART - 1);
  const int tokbase = (blockIdx.x >> 2) * SIMK_BM;
  const int code0 = q * QCODES;
  const int brow = tid >> 2;
  const int bq = (tid & 3) << 3;
  const int t_red = tid >> 1, h_red = tid & 1;

  unsigned e0 = 0, e1 = 0, e2 = 0, e3 = 0;  // top-4 keys, descending
  float t3f = -3.0e38f;  // decoded bucket floor of e3 (valid once e3 != 0)

  f16x8 arh[2], brh[2];

  auto LOADS = [&](int nt, int kt) {
    const int kc = kt * 32 + bq;
#pragma unroll
    for (int i = 0; i < 2; ++i) {
      arh[i] =
          *(const f16x8*)(Apack + (size_t)(tokbase + brow + 64 * i) * 1024 + kc);
      brh[i] =
          *(const f16x8*)(Bhi + (size_t)(code0 + nt + brow + 64 * i) * DIM + kc);
    }
  };
  auto WRITES = [&](int b) {
#pragma unroll
    for (int i = 0; i < 2; ++i) {
      *(f16x8*)(&sm[b][0][(brow + 64 * i) * LDH + bq]) = arh[i];
      *(f16x8*)(&sm[b][1][(brow + 64 * i) * LDH + bq]) = brh[i];
    }
  };

  for (int nt = 0; nt < QCODES; nt += SIMK_BN) {
    f32x16 aHH[2][2];
#pragma unroll
    for (int mb = 0; mb < 2; ++mb)
#pragma unroll
      for (int nb = 0; nb < 2; ++nb) aHH[mb][nb] = (f32x16)0.0f;
    __syncthreads();  // prev epilogue's sC reads done before restaging
    LOADS(nt, 0);
    WRITES(0);
    LOADS(nt, 1);
    LGKM0_FENCE;
    SBAR;
    int cur = 0;
    for (int t = 0; t < 16; ++t) {
      if (t < 15) WRITES(cur ^ 1);
      if (t < 14) LOADS(nt, t + 2);
#pragma unroll
      for (int c = 0; c < 2; ++c) {
        const int ko = c * 16 + lh * 8;
        f16x8 ah[2], bh[2];
#pragma unroll
        for (int mb = 0; mb < 2; ++mb)
          ah[mb] = *(const f16x8*)(&sm[cur][0][(wm * 64 + mb * 32 + lm) * LDH + ko]);
#pragma unroll
        for (int nb = 0; nb < 2; ++nb)
          bh[nb] = *(const f16x8*)(&sm[cur][1][(wn * 64 + nb * 32 + lm) * LDH + ko]);
#pragma unroll
        for (int mb = 0; mb < 2; ++mb)
#pragma unroll
          for (int nb = 0; nb < 2; ++nb)
            aHH[mb][nb] = __builtin_amdgcn_mfma_f32_32x32x16_f16(
                ah[mb], bh[nb], aHH[mb][nb], 0, 0, 0);
      }
      LGKM0_FENCE;
      SBAR;
      cur ^= 1;
    }
    // epilogue: two n-halves through LDS; fast-path top-4 insertion scan
#pragma unroll
    for (int p = 0; p < 2; ++p) {
      __syncthreads();
      if (wn == p) {
#pragma unroll
        for (int mb = 0; mb < 2; ++mb)
#pragma unroll
          for (int nb = 0; nb < 2; ++nb) {
            int nl = nb * 32 + lm;
#pragma unroll
            for (int r = 0; r < 16; ++r) {
              int m = wm * 64 + mb * 32 + (r & 3) + 8 * (r >> 2) + 4 * lh;
              sC[m * 65 + nl] = aHH[mb][nb][r];
            }
          }
      }
      __syncthreads();
      const float* rowp = &sC[t_red * 65 + h_red * 32];
      const int ncomp = 2047 - (code0 + nt + p * 64 + h_red * 32);
#pragma unroll
      for (int i = 0; i < 32; ++i) {
        float v = rowp[i];
        if (v >= t3f) {  // bucket floor => admits every possible insert
          unsigned s = __float_as_uint(v);
          s = (s & 0x80000000u) ? ~s : (s | 0x80000000u);
          unsigned key = (s & 0xFFFFF800u) | (unsigned)(ncomp - i);
          if (key > e3) {
            unsigned y = key, t2;
            t2 = e0 > y ? e0 : y; y = e0 > y ? y : e0; e0 = t2;
            t2 = e1 > y ? e1 : y; y = e1 > y ? y : e1; e1 = t2;
            t2 = e2 > y ? e2 : y; y = e2 > y ? y : e2; e2 = t2;
            e3 = e3 > y ? e3 : y;
            if (e3 != 0u) {  // decode floor (0 encodes "empty" -> keep -inf)
              unsigned d = e3 & 0xFFFFF800u;
              t3f = (d & 0x80000000u) ? __uint_as_float(d & 0x7FFFFFFFu)
                                      : __uint_as_float(~d);
            }
          }
        }
      }
    }
  }
  // merge the two half-lane lists (partition of this quarter's codes)
  unsigned o0 = __shfl_xor(e0, 1), o1 = __shfl_xor(e1, 1),
           o2 = __shfl_xor(e2, 1), o3 = __shfl_xor(e3, 1);
#define INS4(x)                                    \
  {                                                \
    unsigned y = (x), t2;                          \
    t2 = e0 > y ? e0 : y; y = e0 > y ? y : e0; e0 = t2; \
    t2 = e1 > y ? e1 : y; y = e1 > y ? y : e1; e1 = t2; \
    t2 = e2 > y ? e2 : y; y = e2 > y ? y : e2; e2 = t2; \
    e3 = e3 > y ? e3 : y;                          \
  }
  INS4(o0) INS4(o1) INS4(o2) INS4(o3)
  if (h_red == 0) {
    unsigned* cp = cand + ((size_t)(tokbase + t_red) * NQUART + q) * 4;
    cp[0] = e0; cp[1] = e1; cp[2] = e2; cp[3] = e3;
  }
}

// ---------------- exact refine over 16 candidates per token -----------
// Margin test scaled by ||zf_hi|| (zf is unnormalized):
//   split error per sim <= 2^-10 * ||zf||;  key truncation <= 2^-11*|v|.
//   THETA = 2.0e-3*||zf_hi|| + 2^-10*(|v1|+|v2|) + slop.
__global__ __launch_bounds__(256) void k_refine(
    const unsigned* __restrict__ cand, const _Float16* __restrict__ zf16,
    const _Float16* __restrict__ embhi, const _Float16* __restrict__ emblo,
    int* __restrict__ idx, float* __restrict__ idxf) {
  const int tok = (blockIdx.x << 2) + (threadIdx.x >> 6);
  const int lane = threadIdx.x & 63;
  // ||zf_hi||^2 across the wave (also warms cache for exact path)
  f16x8 zh8 = *(const f16x8*)(zf16 + (size_t)tok * 1024 + lane * 8);
  float ss = 0.0f;
#pragma unroll
  for (int j = 0; j < 8; ++j) {
    float x = (float)zh8[j];
    ss += x * x;
  }
#pragma unroll
  for (int off = 1; off < 64; off <<= 1) ss += __shfl_xor(ss, off);

  unsigned k32 = (lane < 16) ? cand[(size_t)tok * 16 + lane] : 0u;
  // wave-wide top-2 of the 16 keys
  unsigned m1 = k32, m2 = 0;
#pragma unroll
  for (int off = 1; off < 64; off <<= 1) {
    unsigned q1 = __shfl_xor(m1, off), q2 = __shfl_xor(m2, off);
    unsigned hi = m1 > q1 ? m1 : q1;
    unsigned lo = m1 > q1 ? q1 : m1;
    unsigned s2 = m2 > q2 ? m2 : q2;
    m2 = lo > s2 ? lo : s2;
    m1 = hi;
  }
  unsigned s1 = m1 & 0xFFFFF800u, s2e = m2 & 0xFFFFF800u;
  float v1 = __uint_as_float((s1 & 0x80000000u) ? (s1 & 0x7FFFFFFFu) : ~s1);
  float v2 = __uint_as_float((s2e & 0x80000000u) ? (s2e & 0x7FFFFFFFu) : ~s2e);
  float theta = 2.0e-3f * sqrtf(ss) +
                9.765625e-4f * (fabsf(v1) + fabsf(v2)) + 1e-6f;
  if (v1 - v2 >= theta) {
    if (lane == 0) {
      int n1 = 2047 - (int)(m1 & 0x7FFu);
      idx[tok] = n1;
      idxf[tok] = (float)n1;
    }
    return;
  }
  // exact path: lane -> (candidate c = lane&15, dim segment seg = lane>>4)
  const int c = lane & 15, seg = lane >> 4;
  unsigned ck = __shfl(k32, c);
  int n = 2047 - (int)(ck & 0x7FFu);
  const _Float16* zh = zf16 + (size_t)tok * 1024 + seg * 128;
  const _Float16* eh = embhi + (size_t)n * DIM + seg * 128;
  const _Float16* el = emblo + (size_t)n * DIM + seg * 128;
  float s = 0.0f;
#pragma unroll
  for (int d = 0; d < 128; d += 8) {
    f16x8 a = *(const f16x8*)(zh + d);
    f16x8 b = *(const f16x8*)(zh + 512 + d);
    f16x8 e = *(const f16x8*)(eh + d);
    f16x8 f = *(const f16x8*)(el + d);
#pragma unroll
    for (int j = 0; j < 8; ++j)
      s += ((float)a[j] + (float)b[j] * (1.0f / 2048.0f)) *
           ((float)e[j] + (float)f[j] * (1.0f / 2048.0f));
  }
  s += __shfl_xor(s, 16);
  s += __shfl_xor(s, 32);
  unsigned sb = __float_as_uint(s);
  sb = (sb & 0x80000000u) ? ~sb : (sb | 0x80000000u);
  unsigned long long kk =
      ((unsigned long long)sb << 32) | (unsigned)(2047 - n);
  if (lane >= 16) kk = 0ull;
#pragma unroll
  for (int off = 1; off < 16; off <<= 1) {
    unsigned long long o = __shfl_xor(kk, off);
    kk = o > kk ? o : kk;
  }
  if (lane == 0) {
    int nb = 2047 - (int)((unsigned)kk & 0x7FFu);
    idx[tok] = nb;
    idxf[tok] = (float)nb;
  }
}

extern "C" void kernel_launch(void* const* d_in, const int* in_sizes, int n_in,
                              void* d_out, int out_size, void* d_ws,
                              size_t ws_size, hipStream_t stream) {
  const float* z = (const float*)d_in[0];
  // d_in[1] = mask, unused
  const float* W_in = (const float*)d_in[2];
  const float* b_in = (const float*)d_in[3];
  const float* W_out = (const float*)d_in[4];
  const float* b_out = (const float*)d_in[5];
  const float* emb = (const float*)d_in[6];

  float* out = (float*)d_out;
  float* zq = out;                           // 32768*512 fp32 (final output)
  float* idxf = out + (size_t)BS_TOK * DIM;  // 32768 fp32 indices

  // ws layout (10.125 MB): embhi|emblo|winhi|winlo|wouthi|woutlo|idx|scratch
  // scratch holds cand (2 MB, dead after refine) then table (4 MB) overlaid.
  _Float16* embhi = (_Float16*)d_ws;
  _Float16* emblo = embhi + (size_t)NCODE * DIM;
  _Float16* winhi = emblo + (size_t)NCODE * DIM;
  _Float16* winlo = winhi + (size_t)DIM * DIM;
  _Float16* wouthi = winlo + (size_t)DIM * DIM;
  _Float16* woutlo = wouthi + (size_t)DIM * DIM;
  int* idx = (int*)(woutlo + (size_t)DIM * DIM);
  unsigned* cand = (unsigned*)(idx + BS_TOK);
  float* table = (float*)cand;  // overlay; written only after refine

  // zf16 packed rows [hi 512 | lo 512] live in the zq output region
  _Float16* zf16 = (_Float16*)zq;

  // 0) split weights
  k_split_w<<<DIM * DIM / 1024, 256, 0, stream>>>(W_in, winhi, winlo);
  k_split_w<<<DIM * DIM / 1024, 256, 0, stream>>>(W_out, wouthi, woutlo);
  // 1) normalize + split codebook rows -> ws
  k_rownorm_split<<<NCODE, 256, 0, stream>>>(emb, embhi, emblo, DIM);
  // 2) zf16 = split(z @ W_in^T + b_in)  (UNNORMALIZED; fused epilogue)
  k_gemm_mfma_in<<<dim3(DIM / 128, BS_TOK / 128), 256, 0, stream>>>(
      z, winhi, winlo, b_in, zf16);
  // 3) hi-only MFMA similarity -> top-4 candidates per (token, quarter)
  k_sim_argmax<<<(BS_TOK / SIMK_BM) * NQUART, 256, 0, stream>>>(zf16, embhi,
                                                                cand);
  // 4) exact refine -> idx (ws) + idxf (d_out)
  k_refine<<<BS_TOK / 4, 256, 0, stream>>>(cand, zf16, embhi, emblo, idx,
                                           idxf);
  // 5) codebook output table (2048 rows; overlays dead cand region)
  k_gemm_codebook<<<dim3(DIM / 128, NCODE / 128), 256, 0, stream>>>(
      embhi, emblo, wouthi, woutlo, b_out, table);
  // 6) zq = z + (table[idx] - z)  (overwrites zf16 region)
  k_gather_st<<<BS_TOK * (DIM / 4) / 256, 256, 0, stream>>>(z, table, idx,
                                                            zq);
}